// Round 1
// baseline (16860.039 us; speedup 1.0000x reference)
//
#include <hip/hip_runtime.h>

#define NLAYER 6
#define NB     128     // batch
#define NT     512     // seq len
#define DIN    128     // layer-0 input size
#define NH     256     // hidden
#define NGRP   2       // batch groups
#define BSZ    64      // batch per group
#define NSLC   16      // hidden-slices per layer
#define HS     16      // hidden per slice  -> 64 gate rows per block
#define NBLK   (NLAYER*NSLC*NGRP)     // 192 blocks, <=256 CUs, all co-resident
#define SLOT_ELT (NB*NH)              // ring slot elements (bf16), 32768
#define FLAG_INTS (2*NLAYER*NGRP*NT)  // C + R arrays
#define FLAG_BYTES (FLAG_INTS*4)      // 49152

typedef __attribute__((ext_vector_type(8))) short short8;
typedef __attribute__((ext_vector_type(4))) float f32x4;

__device__ __forceinline__ unsigned f2bf2(float lo, float hi){
  unsigned a = __float_as_uint(lo), b = __float_as_uint(hi);
  a = (a + 0x7fffu + ((a>>16)&1u)) >> 16;   // RNE bf16
  b = (b + 0x7fffu + ((b>>16)&1u)) >> 16;
  return a | (b<<16);
}

__device__ __forceinline__ uint4 ld8f_bf(const float* p){
  f32x4 a = *(const f32x4*)p;
  f32x4 b = *(const f32x4*)(p+4);
  uint4 r;
  r.x = f2bf2(a[0],a[1]); r.y = f2bf2(a[2],a[3]);
  r.z = f2bf2(b[0],b[1]); r.w = f2bf2(b[2],b[3]);
  return r;
}

__device__ __forceinline__ float sigmf(float v){ return 1.0f/(1.0f + __expf(-v)); }
__device__ __forceinline__ float tanhfast(float v){
  v = fminf(fmaxf(v, -15.0f), 15.0f);
  float e = __expf(2.0f*v);
  return (e - 1.0f)/(e + 1.0f);
}

__device__ __forceinline__ int ld_flag(int* p){
  return __hip_atomic_load(p, __ATOMIC_ACQUIRE, __HIP_MEMORY_SCOPE_AGENT);
}
__device__ __forceinline__ void bump(int* p){
  __hip_atomic_fetch_add(p, 1, __ATOMIC_RELEASE, __HIP_MEMORY_SCOPE_AGENT);
}
__device__ __forceinline__ void waitge(int* p, int v){
  int guard = 0;
  while (ld_flag(p) < v){
    __builtin_amdgcn_s_sleep(1);
    if (++guard > (1<<22)) break;   // failsafe: never triggers in a healthy run
  }
}

// 192 blocks x 256 threads. Block (l, s, g): layer l, hidden slice s (16 h), batch group g (64 b).
// Weights (w_ih||w_hh slice, bf16, MFMA-A-swizzled) stationary in LDS. h exchanged via global ring.
__global__ __launch_bounds__(256, 1)
void lstm_pipe(const float* __restrict__ x,   const float* __restrict__ h0,
               const float* __restrict__ c0,  const float* __restrict__ wih0,
               const float* __restrict__ wih, const float* __restrict__ whh,
               const float* __restrict__ bih, const float* __restrict__ bhh,
               float* __restrict__ out, int* __restrict__ flags,
               unsigned short* __restrict__ ring, int Wv)
{
  __shared__ __align__(16) unsigned char s_w[65536];   // A tiles: [4 gates][KIT][64 lanes * 16B]
  __shared__ __align__(16) unsigned char s_b[66560];   // B buf: [64 batch rows][(Ktot+8) bf16]

  const int tid  = threadIdx.x;
  const int bid  = blockIdx.x;
  const int l    = bid >> 5;          // 32 blocks per layer
  const int s    = (bid >> 1) & 15;
  const int g    = bid & 1;

  const int Kin  = (l == 0) ? DIN : NH;
  const int Ktot = Kin + NH;          // 384 or 512
  const int KIT  = Ktot >> 5;         // 12 or 16 k-iterations of 32
  const int BPITCH = (Ktot + 8) * 2;  // bytes per B row (+8 bf16 pad: bank skew)

  const int lane = tid & 63;
  const int wv   = tid >> 6;          // wave = N-tile (batch block of 16)
  const int quad = lane >> 4;
  const int l15  = lane & 15;

  int* Cbase = flags;                         // arrival counters [L][G][T]
  int* Rbase = flags + NLAYER*NGRP*NT;        // read-token counters [L][G][T]
  int* Cf     = Cbase + (l*NGRP + g)*NT;
  int* CfPrev = Cbase + ((l > 0 ? l-1 : 0)*NGRP + g)*NT;
  int* Rf     = Rbase + (l*NGRP + g)*NT;
  int* RfPrev = Rbase + ((l > 0 ? l-1 : 0)*NGRP + g)*NT;

  // ---- one-time: stage weight slice into LDS, pre-swizzled as MFMA A fragments ----
  // A layout (16x16x32 bf16): lane holds A[m=lane&15][k = (lane>>4)*8 + 0..7]
  for (int idx = tid; idx < 4*KIT*64; idx += 256){
    int lc   = idx & 63;
    int t2   = idx >> 6;
    int kt   = t2 % KIT;
    int q    = t2 / KIT;                       // gate 0..3 (i,f,g,o)
    int grow = q*NH + s*HS + (lc & 15);        // global 4H row
    int k0   = kt*32 + (lc >> 4)*8;
    const float* src;
    if (k0 < Kin){
      src = (l == 0) ? (wih0 + (size_t)grow*DIN + k0)
                     : (wih + (size_t)(l-1)*(4*NH*NH) + (size_t)grow*NH + k0);
    } else {
      src = whh + (size_t)l*(4*NH*NH) + (size_t)grow*NH + (k0 - Kin);
    }
    *(uint4*)(s_w + (q*KIT + kt)*1024 + lc*16) = ld8f_bf(src);
  }

  // ---- per-lane constants ----
  const int brow = wv*16 + l15;      // batch row within group [0,64)
  const int bloc = g*BSZ + brow;     // global batch [0,128)
  const int jcol = s*HS + quad*4;    // first of this lane's 4 hidden cols

  f32x4 bsv[4];
  #pragma unroll
  for (int q = 0; q < 4; ++q){
    f32x4 a = *(const f32x4*)(bih + (size_t)l*4*NH + q*NH + jcol);
    f32x4 b = *(const f32x4*)(bhh + (size_t)l*4*NH + q*NH + jcol);
    bsv[q] = a + b;
  }
  float cc[4];
  {
    f32x4 cv = *(const f32x4*)(c0 + ((size_t)l*NB + bloc)*NH + jcol);
    cc[0]=cv[0]; cc[1]=cv[1]; cc[2]=cv[2]; cc[3]=cv[3];
  }

  const int Wm   = Wv - 1;           // Wv is power of two
  const int K4   = Ktot >> 2;        // staging cols per thread
  const int srow = tid >> 2;         // staging row (batch)
  const int scq  = tid & 3;

  for (int t = 0; t < NT; ++t){
    // ---- wait for inputs (and ring slot reuse if Wv < NT) ----
    if (tid == 0){
      if (t > 0)  waitge(Cf + (t-1), NSLC);          // own layer h_{t-1} complete
      if (l > 0)  waitge(CfPrev + t, NSLC);          // below layer output at t
      if (t >= Wv) waitge(Rf + (t - Wv), (l < NLAYER-1) ? 2*NSLC : NSLC); // slot free
    }
    __syncthreads();

    // ---- stage B = [x_t || h_{t-1}] as bf16 rows into LDS ----
    {
      unsigned char* dstrow = s_b + srow*BPITCH;
      for (int c = 0; c < K4; c += 8){
        int col = scq*K4 + c;
        uint4 v;
        if (col < Kin){
          if (l == 0){
            v = ld8f_bf(x + (size_t)(g*BSZ + srow)*(NT*DIN) + (size_t)t*DIN + col);
          } else {
            const unsigned short* p = ring + ((size_t)(l-1)*Wv + (t & Wm))*SLOT_ELT
                                          + (size_t)(g*BSZ + srow)*NH + col;
            v = *(const uint4*)p;
          }
        } else {
          int hk = col - Kin;
          if (t == 0){
            v = ld8f_bf(h0 + ((size_t)l*NB + g*BSZ + srow)*NH + hk);
          } else {
            const unsigned short* p = ring + ((size_t)l*Wv + ((t-1) & Wm))*SLOT_ELT
                                          + (size_t)(g*BSZ + srow)*NH + hk;
            v = *(const uint4*)p;
          }
        }
        *(uint4*)(dstrow + col*2) = v;
      }
    }
    __syncthreads();

    // read-tokens (back-pressure accounting; only consulted when Wv < NT)
    if (tid == 0  && t > 0) bump(Rf + (t-1));
    if (tid == 64 && l > 0) bump(RfPrev + t);

    // ---- K loop: gates[64 rows x 64 batch] = Wslice @ [x||h]^T, software-prefetched ----
    f32x4 acc0 = {0,0,0,0}, acc1 = {0,0,0,0}, acc2 = {0,0,0,0}, acc3 = {0,0,0,0};
    const unsigned char* bptr = s_b + brow*BPITCH + quad*16;
    const unsigned char* aptr = s_w + lane*16;
    short8 bf = *(const short8*)(bptr);
    short8 a0 = *(const short8*)(aptr + (0*KIT)*1024);
    short8 a1 = *(const short8*)(aptr + (1*KIT)*1024);
    short8 a2 = *(const short8*)(aptr + (2*KIT)*1024);
    short8 a3 = *(const short8*)(aptr + (3*KIT)*1024);
    for (int kt = 0; kt < KIT-1; ++kt){
      short8 bfn = *(const short8*)(bptr + (kt+1)*64);
      short8 a0n = *(const short8*)(aptr + (0*KIT + kt+1)*1024);
      short8 a1n = *(const short8*)(aptr + (1*KIT + kt+1)*1024);
      short8 a2n = *(const short8*)(aptr + (2*KIT + kt+1)*1024);
      short8 a3n = *(const short8*)(aptr + (3*KIT + kt+1)*1024);
      acc0 = __builtin_amdgcn_mfma_f32_16x16x32_bf16(a0, bf, acc0, 0, 0, 0);
      acc1 = __builtin_amdgcn_mfma_f32_16x16x32_bf16(a1, bf, acc1, 0, 0, 0);
      acc2 = __builtin_amdgcn_mfma_f32_16x16x32_bf16(a2, bf, acc2, 0, 0, 0);
      acc3 = __builtin_amdgcn_mfma_f32_16x16x32_bf16(a3, bf, acc3, 0, 0, 0);
      bf = bfn; a0 = a0n; a1 = a1n; a2 = a2n; a3 = a3n;
    }
    acc0 = __builtin_amdgcn_mfma_f32_16x16x32_bf16(a0, bf, acc0, 0, 0, 0);
    acc1 = __builtin_amdgcn_mfma_f32_16x16x32_bf16(a1, bf, acc1, 0, 0, 0);
    acc2 = __builtin_amdgcn_mfma_f32_16x16x32_bf16(a2, bf, acc2, 0, 0, 0);
    acc3 = __builtin_amdgcn_mfma_f32_16x16x32_bf16(a3, bf, acc3, 0, 0, 0);

    // ---- fused gate nonlinearities + state update (all 4 gates land in this lane) ----
    float hv[4];
    #pragma unroll
    for (int r = 0; r < 4; ++r){
      float ig = sigmf(acc0[r] + bsv[0][r]);
      float fg = sigmf(acc1[r] + bsv[1][r]);
      float gv = tanhfast(acc2[r] + bsv[2][r]);
      float og = sigmf(acc3[r] + bsv[3][r]);
      float cn = fg*cc[r] + ig*gv;
      cc[r] = cn;
      hv[r] = og * tanhfast(cn);
    }

    // publish h_t slice (bf16) to ring
    {
      unsigned short* p = ring + ((size_t)l*Wv + (t & Wm))*SLOT_ELT + (size_t)bloc*NH + jcol;
      uint2 hp; hp.x = f2bf2(hv[0], hv[1]); hp.y = f2bf2(hv[2], hv[3]);
      *(uint2*)p = hp;
    }
    if (t == NT-1){
      f32x4 ov; ov[0]=hv[0]; ov[1]=hv[1]; ov[2]=hv[2]; ov[3]=hv[3];
      *(f32x4*)(out + ((size_t)l*NB + bloc)*NH + jcol) = ov;
    }

    // release: __syncthreads drains all stores (vmcnt(0) before s_barrier),
    // tid0's RELEASE atomic performs the device-scope cache maintenance.
    __threadfence();
    __syncthreads();
    if (tid == 0) bump(Cf + t);
  }
}

extern "C" void kernel_launch(void* const* d_in, const int* in_sizes, int n_in,
                              void* d_out, int out_size, void* d_ws, size_t ws_size,
                              hipStream_t stream)
{
  (void)in_sizes; (void)n_in; (void)out_size;
  const float* x    = (const float*)d_in[0];
  const float* h0   = (const float*)d_in[1];
  const float* c0   = (const float*)d_in[2];
  const float* wih0 = (const float*)d_in[3];
  const float* wih  = (const float*)d_in[4];
  const float* whh  = (const float*)d_in[5];
  const float* bih  = (const float*)d_in[6];
  const float* bhh  = (const float*)d_in[7];

  // ring depth: full T if workspace allows (no back-pressure), else shrink (pow2)
  int Wv = 512;
  while (Wv > 2 &&
         (size_t)FLAG_BYTES + (size_t)Wv * NLAYER * SLOT_ELT * 2 > ws_size)
    Wv >>= 1;

  int* flags = (int*)d_ws;
  unsigned short* ring = (unsigned short*)((char*)d_ws + FLAG_BYTES);

  (void)hipMemsetAsync(d_ws, 0, FLAG_BYTES, stream);
  hipLaunchKernelGGL(lstm_pipe, dim3(NBLK), dim3(256), 0, stream,
                     x, h0, c0, wih0, wih, whh, bih, bhh,
                     (float*)d_out, flags, ring, Wv);
}

// Round 2
// 4374.576 us; speedup vs baseline: 3.8541x; 3.8541x over previous
//
#include <hip/hip_runtime.h>

#define NLAYER 6
#define NB     128     // batch
#define NT     512     // seq len
#define DIN    128     // layer-0 input size
#define NH     256     // hidden
#define NGRP   2       // batch groups
#define BSZ    64      // batch per group
#define NSLC   16      // hidden-slices per layer
#define HS     16      // hidden per slice  -> 64 gate rows per block
#define NBLK   (NLAYER*NSLC*NGRP)     // 192 blocks, <=256 CUs, all co-resident
#define SLOT_U64 (NB*NH/4)            // ring slot in u64 units (4 bf16 each) = 8192
#define FLAG_INTS (2*NLAYER*NGRP*NT)  // C + R arrays
#define FLAG_BYTES (FLAG_INTS*4)      // 49152

typedef __attribute__((ext_vector_type(8))) short short8;
typedef __attribute__((ext_vector_type(4))) float f32x4;

__device__ __forceinline__ unsigned f2bf2(float lo, float hi){
  unsigned a = __float_as_uint(lo), b = __float_as_uint(hi);
  a = (a + 0x7fffu + ((a>>16)&1u)) >> 16;   // RNE bf16
  b = (b + 0x7fffu + ((b>>16)&1u)) >> 16;
  return a | (b<<16);
}
__device__ __forceinline__ unsigned long long f2bf4(float a, float b, float c, float d){
  return (unsigned long long)f2bf2(a,b) | ((unsigned long long)f2bf2(c,d) << 32);
}

__device__ __forceinline__ uint4 ld8f_bf(const float* p){
  f32x4 a = *(const f32x4*)p;
  f32x4 b = *(const f32x4*)(p+4);
  uint4 r;
  r.x = f2bf2(a[0],a[1]); r.y = f2bf2(a[2],a[3]);
  r.z = f2bf2(b[0],b[1]); r.w = f2bf2(b[2],b[3]);
  return r;
}

__device__ __forceinline__ float sigmf(float v){ return 1.0f/(1.0f + __expf(-v)); }
__device__ __forceinline__ float tanhfast(float v){
  v = fminf(fmaxf(v, -15.0f), 15.0f);
  float e = __expf(2.0f*v);
  return (e - 1.0f)/(e + 1.0f);
}

// All cross-block traffic uses RELAXED agent-scope atomics (device-coherent
// sc1 ops at L3, NO buffer_inv / buffer_wbl2 cache maintenance). Ordering:
// __syncthreads drains vmcnt(0), so data stores are ack'd at L3 (the single
// agent coherence point) before the flag bump issues -> real-time order.
__device__ __forceinline__ int ld_flag(int* p){
  return __hip_atomic_load(p, __ATOMIC_RELAXED, __HIP_MEMORY_SCOPE_AGENT);
}
__device__ __forceinline__ void bump(int* p){
  __hip_atomic_fetch_add(p, 1, __ATOMIC_RELAXED, __HIP_MEMORY_SCOPE_AGENT);
}
__device__ __forceinline__ void waitge(int* p, int v){
  int guard = 0;
  while (ld_flag(p) < v){
    __builtin_amdgcn_s_sleep(1);
    if (++guard > (1<<21)) break;   // failsafe only
  }
}
__device__ __forceinline__ unsigned long long ring_ld(const unsigned long long* p){
  return __hip_atomic_load(p, __ATOMIC_RELAXED, __HIP_MEMORY_SCOPE_AGENT);
}
__device__ __forceinline__ void ring_st(unsigned long long* p, unsigned long long v){
  __hip_atomic_store(p, v, __ATOMIC_RELAXED, __HIP_MEMORY_SCOPE_AGENT);
}

// 192 blocks x 256 threads. Block (l, s, g): layer l, hidden slice s (16 h), batch group g (64 b).
// Weights (w_ih||w_hh slice, bf16, MFMA-A-swizzled) stationary in LDS. h exchanged via L3 ring.
__global__ __launch_bounds__(256, 1)
void lstm_pipe(const float* __restrict__ x,   const float* __restrict__ h0,
               const float* __restrict__ c0,  const float* __restrict__ wih0,
               const float* __restrict__ wih, const float* __restrict__ whh,
               const float* __restrict__ bih, const float* __restrict__ bhh,
               float* __restrict__ out, int* __restrict__ flags,
               unsigned long long* __restrict__ ring, int Wv)
{
  __shared__ __align__(16) unsigned char s_w[65536];   // A tiles: [4 gates][KIT][64 lanes * 16B]
  __shared__ __align__(16) unsigned char s_b[66560];   // B buf: [64 batch rows][(Ktot+8) bf16]

  const int tid  = threadIdx.x;
  const int bid  = blockIdx.x;
  const int l    = bid >> 5;          // 32 blocks per layer
  const int s    = (bid >> 1) & 15;
  const int g    = bid & 1;

  const int Kin  = (l == 0) ? DIN : NH;
  const int Ktot = Kin + NH;          // 384 or 512
  const int KIT  = Ktot >> 5;         // 12 or 16 k-iterations of 32
  const int BPITCH = (Ktot + 8) * 2;  // bytes per B row, 16B-aligned

  const int lane = tid & 63;
  const int wv   = tid >> 6;          // wave = N-tile (batch block of 16)
  const int quad = lane >> 4;
  const int l15  = lane & 15;

  int* Cbase = flags;                         // arrival counters [L][G][T]
  int* Rbase = flags + NLAYER*NGRP*NT;        // read-token counters [L][G][T]
  int* Cf     = Cbase + (l*NGRP + g)*NT;
  int* CfPrev = Cbase + ((l > 0 ? l-1 : 0)*NGRP + g)*NT;
  int* Rf     = Rbase + (l*NGRP + g)*NT;
  int* RfPrev = Rbase + ((l > 0 ? l-1 : 0)*NGRP + g)*NT;

  // ---- one-time: stage weight slice into LDS, pre-swizzled as MFMA A fragments ----
  // A layout (16x16x32 bf16): lane holds A[m=lane&15][k = (lane>>4)*8 + 0..7]
  for (int idx = tid; idx < 4*KIT*64; idx += 256){
    int lc   = idx & 63;
    int t2   = idx >> 6;
    int kt   = t2 % KIT;
    int q    = t2 / KIT;                       // gate 0..3 (i,f,g,o)
    int grow = q*NH + s*HS + (lc & 15);        // global 4H row
    int k0   = kt*32 + (lc >> 4)*8;
    const float* src;
    if (k0 < Kin){
      src = (l == 0) ? (wih0 + (size_t)grow*DIN + k0)
                     : (wih + (size_t)(l-1)*(4*NH*NH) + (size_t)grow*NH + k0);
    } else {
      src = whh + (size_t)l*(4*NH*NH) + (size_t)grow*NH + (k0 - Kin);
    }
    *(uint4*)(s_w + (q*KIT + kt)*1024 + lc*16) = ld8f_bf(src);
  }

  // ---- per-lane constants ----
  const int brow = wv*16 + l15;      // batch row within group [0,64)
  const int bloc = g*BSZ + brow;     // global batch [0,128)
  const int jcol = s*HS + quad*4;    // first of this lane's 4 hidden cols

  f32x4 bsv[4];
  #pragma unroll
  for (int q = 0; q < 4; ++q){
    f32x4 a = *(const f32x4*)(bih + (size_t)l*4*NH + q*NH + jcol);
    f32x4 b = *(const f32x4*)(bhh + (size_t)l*4*NH + q*NH + jcol);
    bsv[q] = a + b;
  }
  float cc[4];
  {
    f32x4 cv = *(const f32x4*)(c0 + ((size_t)l*NB + bloc)*NH + jcol);
    cc[0]=cv[0]; cc[1]=cv[1]; cc[2]=cv[2]; cc[3]=cv[3];
  }

  const int Wm   = Wv - 1;           // Wv is power of two
  const int sub  = tid & 3;          // staging: 4 threads per batch row
  const int srow = tid >> 2;         //   consecutive lanes -> consecutive chunks (bank-friendly)
  const int gb   = g*BSZ + srow;
  const int NC   = Ktot >> 2;        // u64 chunks per row (128 or 96)
  const int NI   = NC >> 2;          // chunks per thread (32 or 24)
  const int KinC = Kin >> 2;         // u64 chunks covering the input part

  const unsigned long long* ringPrev = ring + (size_t)(l > 0 ? l-1 : 0)*Wv*SLOT_U64;
  unsigned long long*       ringOwn  = ring + (size_t)l*Wv*SLOT_U64;

  for (int t = 0; t < NT; ++t){
    // ---- wait for inputs (3 parallel pollers), relaxed polls only ----
    if (tid == 0){
      if (t > 0)  waitge(Cf + (t-1), NSLC);          // own layer h_{t-1} complete
    } else if (tid == 64){
      if (l > 0)  waitge(CfPrev + t, NSLC);          // below layer output at t
    } else if (tid == 128){
      if (t >= Wv) waitge(Rf + (t - Wv), (l < NLAYER-1) ? 2*NSLC : NSLC); // slot free
    }
    __syncthreads();

    // ---- stage B = [x_t || h_{t-1}] as bf16 rows into LDS ----
    {
      unsigned char* dstrow = s_b + srow*BPITCH;
      for (int i = 0; i < NI; ++i){
        int c = sub + 4*i;                       // u64 chunk within row
        unsigned long long v;
        if (c < KinC){
          if (l == 0){
            const float* px = x + (size_t)gb*(NT*DIN) + (size_t)t*DIN + c*4;
            f32x4 a = *(const f32x4*)px;
            v = f2bf4(a[0],a[1],a[2],a[3]);
          } else {
            v = ring_ld(ringPrev + (size_t)(t & Wm)*SLOT_U64 + (size_t)gb*64 + c);
          }
        } else {
          int hc = c - KinC;
          if (t == 0){
            const float* ph = h0 + ((size_t)l*NB + gb)*NH + hc*4;
            f32x4 a = *(const f32x4*)ph;
            v = f2bf4(a[0],a[1],a[2],a[3]);
          } else {
            v = ring_ld(ringOwn + (size_t)((t-1) & Wm)*SLOT_U64 + (size_t)gb*64 + hc);
          }
        }
        *(unsigned long long*)(dstrow + c*8) = v;
      }
    }
    __syncthreads();

    // read-tokens (back-pressure accounting)
    if (tid == 0  && t > 0) bump(Rf + (t-1));
    if (tid == 64 && l > 0) bump(RfPrev + t);

    // ---- K loop: gates[64 rows x 64 batch] = Wslice @ [x||h]^T, software-prefetched ----
    f32x4 acc0 = {0,0,0,0}, acc1 = {0,0,0,0}, acc2 = {0,0,0,0}, acc3 = {0,0,0,0};
    const unsigned char* bptr = s_b + brow*BPITCH + quad*16;
    const unsigned char* aptr = s_w + lane*16;
    short8 bf = *(const short8*)(bptr);
    short8 a0 = *(const short8*)(aptr + (0*KIT)*1024);
    short8 a1 = *(const short8*)(aptr + (1*KIT)*1024);
    short8 a2 = *(const short8*)(aptr + (2*KIT)*1024);
    short8 a3 = *(const short8*)(aptr + (3*KIT)*1024);
    for (int kt = 0; kt < KIT-1; ++kt){
      short8 bfn = *(const short8*)(bptr + (kt+1)*64);
      short8 a0n = *(const short8*)(aptr + (0*KIT + kt+1)*1024);
      short8 a1n = *(const short8*)(aptr + (1*KIT + kt+1)*1024);
      short8 a2n = *(const short8*)(aptr + (2*KIT + kt+1)*1024);
      short8 a3n = *(const short8*)(aptr + (3*KIT + kt+1)*1024);
      acc0 = __builtin_amdgcn_mfma_f32_16x16x32_bf16(a0, bf, acc0, 0, 0, 0);
      acc1 = __builtin_amdgcn_mfma_f32_16x16x32_bf16(a1, bf, acc1, 0, 0, 0);
      acc2 = __builtin_amdgcn_mfma_f32_16x16x32_bf16(a2, bf, acc2, 0, 0, 0);
      acc3 = __builtin_amdgcn_mfma_f32_16x16x32_bf16(a3, bf, acc3, 0, 0, 0);
      bf = bfn; a0 = a0n; a1 = a1n; a2 = a2n; a3 = a3n;
    }
    acc0 = __builtin_amdgcn_mfma_f32_16x16x32_bf16(a0, bf, acc0, 0, 0, 0);
    acc1 = __builtin_amdgcn_mfma_f32_16x16x32_bf16(a1, bf, acc1, 0, 0, 0);
    acc2 = __builtin_amdgcn_mfma_f32_16x16x32_bf16(a2, bf, acc2, 0, 0, 0);
    acc3 = __builtin_amdgcn_mfma_f32_16x16x32_bf16(a3, bf, acc3, 0, 0, 0);

    // ---- fused gate nonlinearities + state update (all 4 gates land in this lane) ----
    float hv[4];
    #pragma unroll
    for (int r = 0; r < 4; ++r){
      float ig = sigmf(acc0[r] + bsv[0][r]);
      float fg = sigmf(acc1[r] + bsv[1][r]);
      float gv = tanhfast(acc2[r] + bsv[2][r]);
      float og = sigmf(acc3[r] + bsv[3][r]);
      float cn = fg*cc[r] + ig*gv;
      cc[r] = cn;
      hv[r] = og * tanhfast(cn);
    }

    // publish h_t slice (bf16, 8B device-coherent store into L3 ring)
    ring_st(ringOwn + (size_t)(t & Wm)*SLOT_U64 + (size_t)bloc*64 + s*4 + quad,
            f2bf4(hv[0], hv[1], hv[2], hv[3]));

    if (t == NT-1){
      f32x4 ov; ov[0]=hv[0]; ov[1]=hv[1]; ov[2]=hv[2]; ov[3]=hv[3];
      *(f32x4*)(out + ((size_t)l*NB + bloc)*NH + jcol) = ov;
    }

    // release: barrier drains vmcnt(0) (ring stores ack'd at L3), then bump.
    __syncthreads();
    if (tid == 0) bump(Cf + t);
  }
}

extern "C" void kernel_launch(void* const* d_in, const int* in_sizes, int n_in,
                              void* d_out, int out_size, void* d_ws, size_t ws_size,
                              hipStream_t stream)
{
  (void)in_sizes; (void)n_in; (void)out_size;
  const float* x    = (const float*)d_in[0];
  const float* h0   = (const float*)d_in[1];
  const float* c0   = (const float*)d_in[2];
  const float* wih0 = (const float*)d_in[3];
  const float* wih  = (const float*)d_in[4];
  const float* whh  = (const float*)d_in[5];
  const float* bih  = (const float*)d_in[6];
  const float* bhh  = (const float*)d_in[7];

  // small L3-resident ring (back-pressure keeps producers <= Wv ahead)
  int Wv = 16;
  while (Wv > 2 &&
         (size_t)FLAG_BYTES + (size_t)Wv * NLAYER * SLOT_U64 * 8 > ws_size)
    Wv >>= 1;

  int* flags = (int*)d_ws;
  unsigned long long* ring = (unsigned long long*)((char*)d_ws + FLAG_BYTES);

  (void)hipMemsetAsync(d_ws, 0, FLAG_BYTES, stream);
  hipLaunchKernelGGL(lstm_pipe, dim3(NBLK), dim3(256), 0, stream,
                     x, h0, c0, wih0, wih, whh, bih, bhh,
                     (float*)d_out, flags, ring, Wv);
}